// Round 12
// baseline (1741.093 us; speedup 1.0000x reference)
//
#include <hip/hip_runtime.h>

#define T_STEPS 1000
#define BATCH   256
#define NHID    200
#define ROWF    204      // floats per LDS row: 200 output weights + W2[i] + 3 pad
#define BETA_C  0.85f
#define THR_C   1.0f
#define SENT    (1ull << 50)
#define NSLOT   12       // static gather slots per 50-neuron word

// OUTPUT-split: wave w owns output neurons [50w,50w+50), one per lane.
// LDS row i (SOURCE neuron i): float o = Wrec[o][i] for o in [0,200), and
// float 200 = W2[i]. Lane l of wave w reads row i at float offset 50w+l
// (lanes >=50 read offset 200 -> accumulate cur2 for free). Consecutive
// lanes read consecutive floats -> conflict-free.
// Cross-wave exchange per step = 4 x u64 spike masks, double-buffered in
// LDS -> ONE lgkm-only barrier per step (spike stores stay fire-and-forget).

__launch_bounds__(256, 1)
__global__ void rsnn_kernel(const float* __restrict__ X,
                            const float* __restrict__ W1,
                            const float* __restrict__ b1,
                            const float* __restrict__ Wrec,
                            const float* __restrict__ brec,
                            const float* __restrict__ W2,
                            const float* __restrict__ b2,
                            float* __restrict__ out_cur2,
                            float* __restrict__ out_spk) {
#pragma clang fp contract(off)
    __shared__ float              WT2[NHID * ROWF];   // 163,200 B
    __shared__ unsigned long long mask_lds[2][4];     //      64 B

    const int tid = threadIdx.x;
    const int l   = tid & 63;            // lane
    const int w   = tid >> 6;            // wave id = output word id
    const int b   = blockIdx.x;

    // ---- stage Wrec transposed (source-major) + W2 column into LDS ----
    for (int idx = tid; idx < NHID * NHID; idx += 256) {
        int r = idx / NHID;              // Wrec row  (output neuron)
        int i = idx - r * NHID;          // Wrec col  (source neuron)
        WT2[i * ROWF + r] = Wrec[idx];
    }
    for (int i = tid; i < NHID; i += 256) WT2[i * ROWF + 200] = W2[i];
    if (tid < 4) mask_lds[0][tid] = 0ull;   // step-0 masks = empty
    __syncthreads();

    // ---- per-lane parameters (one output neuron per lane) ----
    const int oc    = (l < 50) ? 50 * w + l : 199;  // clamped for param loads
    const int o_lds = (l < 50) ? 50 * w + l : 200;  // W2 column for idle lanes
    const float w10 = W1[oc * 3 + 0], w11 = W1[oc * 3 + 1], w12 = W1[oc * 3 + 2];
    const float b1j = b1[oc], brj = brec[oc];
    const float b2v = b2[0];

    float mem = 0.f;

    const float* xp = X + (size_t)b * 3;
    float x0 = xp[0], x1 = xp[1], x2 = xp[2];

    const float* lds_lane = WT2 + o_lds;
    float*       spk_out  = out_spk + (size_t)b * NHID + oc;

    for (int t = 0; t <= T_STEPS; ++t) {
        // ---- read the 4 spike-mask words (uniform broadcast reads) ----
        const int p = t & 1;
        unsigned long long mw[4];
#pragma unroll
        for (int W = 0; W < 4; ++W) {
            unsigned long long v = mask_lds[p][W];
            mw[W] = (((unsigned long long)__builtin_amdgcn_readfirstlane(
                         (unsigned)(v >> 32))) << 32) |
                    (unsigned long long)(unsigned)__builtin_amdgcn_readfirstlane(
                        (unsigned)v);
        }

        // prefetch next step's input
        int   tn  = (t + 1 < T_STEPS) ? t + 1 : 0;
        float nx0 = xp[(size_t)tn * BATCH * 3 + 0];
        float nx1 = xp[(size_t)tn * BATCH * 3 + 1];
        float nx2 = xp[(size_t)tn * BATCH * 3 + 2];

        // ---- extract 48 sentinel-gated slots; issue all 48 b32 loads ----
        float vs[4][NSLOT], gs[4][NSLOT];
#pragma unroll
        for (int W = 0; W < 4; ++W) {
            unsigned long long m = mw[W];
#pragma unroll
            for (int K = 0; K < NSLOT; ++K) {
                unsigned long long mm = m | SENT;
                int rr = __builtin_ctzll(mm);
                int ii = rr > 49 ? 49 : rr;
                gs[W][K] = (m != 0ull) ? 1.f : 0.f;
                m &= m - 1;
                vs[W][K] = lds_lane[(50 * W + ii) * ROWF];
            }
            mw[W] = m;   // leftover bits (rare)
        }

        // ---- consume in ascending source order (gated fma is bit-exact) ----
        float rec = 0.f;
#pragma unroll
        for (int W = 0; W < 4; ++W) {
#pragma unroll
            for (int K = 0; K < NSLOT; ++K)
                rec = fmaf(gs[W][K], vs[W][K], rec);
            unsigned long long m = mw[W];
            while (m) {   // leftover: exact, in order
                int i = __builtin_ctzll(m); m &= m - 1;
                rec += lds_lane[(50 * W + i) * ROWF];
            }
        }

        // lanes >=50 accumulated W2 over firing set of t-1 = cur2_{t-1}
        if (t > 0 && w == 0 && l == 50)
            out_cur2[(size_t)(t - 1) * BATCH + b] = rec + b2v;

        if (t == T_STEPS) break;   // last iteration: cur2 flush only

        // ---- membrane update (numpy op/rounding order preserved) ----
        float c1  = fmaf(x2, w12, fmaf(x1, w11, x0 * w10)) + b1j;
        float ba  = ((BETA_C * mem + c1) + rec) + brj;
        float nm  = (mem > THR_C) ? 0.f : ba;
        float sp  = (nm > THR_C) ? 1.f : 0.f;
        mem = nm;

        // ---- spike store (fire-and-forget; never drained by barrier) ----
        if (l < 50)
            spk_out[(size_t)t * BATCH * NHID] = sp;

        // ---- publish this wave's mask word for next step ----
        unsigned long long wd = __ballot((l < 50) && (sp > 0.5f));
        if (l == 0) mask_lds[p ^ 1][w] = wd;

        x0 = nx0; x1 = nx1; x2 = nx2;

        // ---- single per-step barrier: LDS-only drain ----
        asm volatile("s_waitcnt lgkmcnt(0)\n\ts_barrier" ::: "memory");
    }
}

extern "C" void kernel_launch(void* const* d_in, const int* in_sizes, int n_in,
                              void* d_out, int out_size, void* d_ws, size_t ws_size,
                              hipStream_t stream) {
    const float* X    = (const float*)d_in[0];
    const float* W1   = (const float*)d_in[1];
    const float* b1   = (const float*)d_in[2];
    const float* Wrec = (const float*)d_in[3];
    const float* brec = (const float*)d_in[4];
    const float* W2   = (const float*)d_in[5];
    const float* b2   = (const float*)d_in[6];

    float* out_cur2 = (float*)d_out;                            // [T,B,1] flat
    float* out_spk  = (float*)d_out + (size_t)T_STEPS * BATCH;  // [T,B,200] flat

    rsnn_kernel<<<BATCH, 256, 0, stream>>>(X, W1, b1, Wrec, brec, W2, b2,
                                           out_cur2, out_spk);
}

// Round 13
// 601.877 us; speedup vs baseline: 2.8928x; 2.8928x over previous
//
#include <hip/hip_runtime.h>

#define T_STEPS 1000
#define BATCH   256
#define NHID    200
#define ROWF    200      // floats per LDS row (800 B, 16B-aligned)
#define BETA_C  0.85f
#define THR_C   1.0f

// WT2 row i (source neuron i) holds at float offset lo*4+k (lo<50,k<4):
// Wrec[(lo+50k)][i]. Lane lo reads ONE ds_read_b128 per firing source i,
// yielding weights for outputs {lo, lo+50, lo+100, lo+150}.
//
// 4 waves per batch element; wave w gathers source word w (~7 firing) into
// component partials pr0..pr3, writes them transposed to part[comp][w][lane],
// then reads ONLY its own component row: rec(out=50w+l) = sum over src waves
// in word order. Each wave updates only its 50 neurons and ballots only its
// own word -> no mask exchange at all. cur2 is recomputed by a second kernel
// from the stored spikes (removes the shfl-tree straggler from the chain).

__launch_bounds__(256, 1)
__global__ void rsnn_kernel(const float* __restrict__ X,
                            const float* __restrict__ W1,
                            const float* __restrict__ b1,
                            const float* __restrict__ Wrec,
                            const float* __restrict__ brec,
                            float* __restrict__ out_spk) {
#pragma clang fp contract(off)
    __shared__ float WT2[NHID * ROWF];   // 160,000 B
    __shared__ float part[4][4][50];     //   3,200 B  [comp][src wave][lane]

    const int tid = threadIdx.x;
    const int l   = tid & 63;            // lane
    const int w   = tid >> 6;            // wave id = source & output word id
    const int b   = blockIdx.x;

    // ---- stage Wrec (permuted transpose) into LDS ----
    for (int idx = tid; idx < NHID * NHID; idx += 256) {
        int r  = idx / NHID;             // Wrec row  (output neuron)
        int i  = idx - r * NHID;         // Wrec col  (source neuron)
        int lo = r % 50, k = r / 50;
        WT2[i * ROWF + lo * 4 + k] = Wrec[idx];
    }
    __syncthreads();

    const int lc = (l < 50) ? l : 49;    // lanes 50-63 duplicate lane 49
    const int oc = 50 * w + lc;          // this lane's output neuron
    const float w10 = W1[oc * 3 + 0], w11 = W1[oc * 3 + 1], w12 = W1[oc * 3 + 2];
    const float b1j = b1[oc], brj = brec[oc];

    float mem = 0.f;
    unsigned long long bm = 0;           // own word's spike mask

    const float* xp = X + (size_t)b * 3;
    float x0 = xp[0], x1 = xp[1], x2 = xp[2];

    const float* ldsrow  = WT2 + (size_t)lc * 4;
    const int    wbase   = 50 * w;
    float*       spk_out = out_spk + (size_t)b * NHID + wbase + lc;

#define REC_WORD(MASK, BASE)                                                          \
    {                                                                                 \
        unsigned long long m = (MASK);                                                \
        while (m) {                                                                   \
            int i0 = __builtin_ctzll(m); m &= m - 1;                                  \
            bool h1 = m != 0; int i1 = h1 ? __builtin_ctzll(m) : i0; if (h1) m &= m - 1; \
            bool h2 = m != 0; int i2 = h2 ? __builtin_ctzll(m) : i0; if (h2) m &= m - 1; \
            bool h3 = m != 0; int i3 = h3 ? __builtin_ctzll(m) : i0; if (h3) m &= m - 1; \
            const float4 v0 = *(const float4*)(ldsrow + (i0 + (BASE)) * ROWF);        \
            const float4 v1 = *(const float4*)(ldsrow + (i1 + (BASE)) * ROWF);        \
            const float4 v2 = *(const float4*)(ldsrow + (i2 + (BASE)) * ROWF);        \
            const float4 v3 = *(const float4*)(ldsrow + (i3 + (BASE)) * ROWF);        \
            pr0 += v0.x; pr1 += v0.y; pr2 += v0.z; pr3 += v0.w;                       \
            if (h1) { pr0 += v1.x; pr1 += v1.y; pr2 += v1.z; pr3 += v1.w; }           \
            if (h2) { pr0 += v2.x; pr1 += v2.y; pr2 += v2.z; pr3 += v2.w; }           \
            if (h3) { pr0 += v3.x; pr1 += v3.y; pr2 += v3.z; pr3 += v3.w; }           \
        }                                                                             \
    }

    for (int t = 0; t < T_STEPS; ++t) {
        // prefetch next step's input (used one iteration later)
        int   tn  = (t + 1 < T_STEPS) ? t + 1 : t;
        float nx0 = xp[(size_t)tn * BATCH * 3 + 0];
        float nx1 = xp[(size_t)tn * BATCH * 3 + 1];
        float nx2 = xp[(size_t)tn * BATCH * 3 + 2];

        // ---- A: gather own source word (vectorized b128, as round 10) ----
        float pr0 = 0.f, pr1 = 0.f, pr2 = 0.f, pr3 = 0.f;
        REC_WORD(bm, wbase)

        // ---- B: publish component partials transposed (conflict-free b32) ----
        if (l < 50) {
            part[0][w][l] = pr0;
            part[1][w][l] = pr1;
            part[2][w][l] = pr2;
            part[3][w][l] = pr3;
        }
        asm volatile("s_waitcnt lgkmcnt(0)\n\ts_barrier" ::: "memory");

        // ---- C: own-component reduce over src waves (word-blocked order) ----
        float rec = ((part[w][0][lc] + part[w][1][lc])
                     + part[w][2][lc]) + part[w][3][lc];
        asm volatile("s_waitcnt lgkmcnt(0)\n\ts_barrier" ::: "memory");

        // ---- D: update own neuron only (numpy op/rounding order preserved) ----
        float c1 = fmaf(x2, w12, fmaf(x1, w11, x0 * w10)) + b1j;
        float ba = ((BETA_C * mem + c1) + rec) + brj;
        float nm = (mem > THR_C) ? 0.f : ba;
        float sp = (nm > THR_C) ? 1.f : 0.f;
        mem = nm;

        // ---- E: spike store (fire-and-forget) + own-word ballot ----
        if (l < 50)
            spk_out[(size_t)t * BATCH * NHID] = sp;
        bm = __ballot((l < 50) && (sp > 0.5f));

        x0 = nx0; x1 = nx1; x2 = nx2;
    }
#undef REC_WORD
}

// cur2[t,b] = sum_j spk[t,b,j]*W2[j] + b2 — recomputed from stored spikes
// (L3-resident). Terminal output: tree reduction order is safe.
__launch_bounds__(256)
__global__ void cur2_kernel(const float* __restrict__ spk,
                            const float* __restrict__ W2,
                            const float* __restrict__ b2,
                            float* __restrict__ out) {
    const int lane = threadIdx.x & 63;
    const int wid  = (int)((blockIdx.x * blockDim.x + threadIdx.x) >> 6);
    const int nw   = (int)((gridDim.x * blockDim.x) >> 6);

    float4 w2v = {0.f, 0.f, 0.f, 0.f};
    if (lane < 50) w2v = *(const float4*)(W2 + lane * 4);
    const float b2v = b2[0];

    for (int p = wid; p < T_STEPS * BATCH; p += nw) {
        float4 sv = {0.f, 0.f, 0.f, 0.f};
        if (lane < 50) sv = *(const float4*)(spk + (size_t)p * NHID + lane * 4);
        float a = fmaf(sv.w, w2v.w, fmaf(sv.z, w2v.z,
                  fmaf(sv.y, w2v.y, sv.x * w2v.x)));
#pragma unroll
        for (int o = 32; o >= 1; o >>= 1) a += __shfl_xor(a, o);
        if (lane == 0) out[p] = a + b2v;   // p = t*BATCH + b
    }
}

extern "C" void kernel_launch(void* const* d_in, const int* in_sizes, int n_in,
                              void* d_out, int out_size, void* d_ws, size_t ws_size,
                              hipStream_t stream) {
    const float* X    = (const float*)d_in[0];
    const float* W1   = (const float*)d_in[1];
    const float* b1   = (const float*)d_in[2];
    const float* Wrec = (const float*)d_in[3];
    const float* brec = (const float*)d_in[4];
    const float* W2   = (const float*)d_in[5];
    const float* b2   = (const float*)d_in[6];

    float* out_cur2 = (float*)d_out;                            // [T,B,1] flat
    float* out_spk  = (float*)d_out + (size_t)T_STEPS * BATCH;  // [T,B,200] flat

    rsnn_kernel<<<BATCH, 256, 0, stream>>>(X, W1, b1, Wrec, brec, out_spk);
    cur2_kernel<<<1024, 256, 0, stream>>>(out_spk, W2, b2, out_cur2);
}